// Round 18
// baseline (89.367 us; speedup 1.0000x reference)
//
#include <hip/hip_runtime.h>

// B=16, S=256, IN=128, OUT=128, HID=512
// DIAGNOSTIC ROUND: R17 kernels unchanged; chain {AB, C, D} launched x3
// (idempotent, deterministic) to measure fixed-per-replay overhead F vs
// kernel time K.  R17: F+K=33.2.  This: F+3K.  See round notes.

typedef __attribute__((ext_vector_type(8))) short     s16x8;
typedef __attribute__((ext_vector_type(8))) unsigned short u16x8;
typedef __attribute__((ext_vector_type(4))) float     f32x4;

__device__ __forceinline__ unsigned short f2bf(float f) {
    union { float f; unsigned int u; } v; v.f = f;
    unsigned int r = v.u + 0x7FFFu + ((v.u >> 16) & 1u);   // RNE
    return (unsigned short)(r >> 16);
}
__device__ __forceinline__ float bf2f(unsigned short u) {
    union { unsigned int u; float f; } v; v.u = ((unsigned int)u) << 16;
    return v.f;
}

// ws float offsets
#define OFF_MP   0          // Mp   f32 [2][16][65536] -> 2097152 f
#define OFF_PART 2097152    // part f32 [512][16][128] -> 1048576 f
#define OFF_SXP  3145728    // sxp  f32 [4][16][128]   -> 8192 f

// ---------- Stage AB (R13-proven): GEMM1 (x@W1 -> h in LDS) + GEMM2 (h^T@x -> Mp) ----------
__global__ __launch_bounds__(256) void k_AB(const float* __restrict__ x,
        const float* __restrict__ W1, const float* __restrict__ b1,
        float* __restrict__ Mp, float* __restrict__ sxp) {
    __shared__ __align__(16) unsigned char smem[87296];
    auto Ws  = (unsigned short (*)[136])(smem);            // [64][136] hid x i
    auto xA  = (unsigned short (*)[136])(smem + 17408);    // [128][136] s x i
    auto xTl = (unsigned short (*)[136])(smem + 52224);    // [128][136] i x s
    auto Wt  = (float (*)[33])(smem + 52224);              // f32 staging (alias xTl)
    float* b1s = (float*)(smem + 87040);
    auto hts = (unsigned short (*)[136])(smem);            // [64][136] alias Ws

    const int tid = threadIdx.x;
    const int b  = blockIdx.x >> 4;
    const int hb = (blockIdx.x >> 1) & 7;
    const int sh = blockIdx.x & 1;

    {
        const int r = tid >> 1, q = tid & 1;
        const float* xrow = &x[(size_t)(b * 256 + sh * 128 + r) * 128 + q * 64];
        #pragma unroll
        for (int m = 0; m < 8; ++m) {
            const float4 v0 = *(const float4*)&xrow[m * 8];
            const float4 v1 = *(const float4*)&xrow[m * 8 + 4];
            unsigned short t8[8] __attribute__((aligned(16))) = {
                f2bf(v0.x), f2bf(v0.y), f2bf(v0.z), f2bf(v0.w),
                f2bf(v1.x), f2bf(v1.y), f2bf(v1.z), f2bf(v1.w)};
            *(u16x8*)&xA[r][q * 64 + m * 8] = *(u16x8*)t8;
        }
        if (tid < 64) b1s[tid] = b1[hb * 64 + tid];
    }
    for (int hq = 0; hq < 2; ++hq) {
        __syncthreads();
        #pragma unroll
        for (int p = 0; p < 16; ++p) {
            const int flat = p * 256 + tid;
            const int i = flat >> 5, hc = flat & 31;
            Wt[i][hc] = W1[(size_t)i * 512 + hb * 64 + hq * 32 + hc];
        }
        __syncthreads();
        {
            const int h2 = tid >> 3, pt = tid & 7;
            unsigned short t16[16] __attribute__((aligned(16)));
            #pragma unroll
            for (int m = 0; m < 16; ++m)
                t16[m] = f2bf(Wt[pt * 16 + m][h2]);
            *(u16x8*)&Ws[hq * 32 + h2][pt * 16]     = *(u16x8*)&t16[0];
            *(u16x8*)&Ws[hq * 32 + h2][pt * 16 + 8] = *(u16x8*)&t16[8];
        }
    }
    __syncthreads();

    const int w = tid >> 6, lane = tid & 63;
    const int wr = w >> 1, wc = w & 1;
    const int l15 = lane & 15, kl = lane >> 4;
    f32x4 zero = {0.f, 0.f, 0.f, 0.f};

    // GEMM1: C[tok 128][hid 64]; wave tile 64x32
    f32x4 acc[4][2];
    #pragma unroll
    for (int i = 0; i < 4; ++i)
        #pragma unroll
        for (int j = 0; j < 2; ++j) acc[i][j] = zero;
    #pragma unroll
    for (int ks = 0; ks < 4; ++ks) {
        s16x8 a[4], bb[2];
        #pragma unroll
        for (int f = 0; f < 4; ++f)
            a[f] = *(const s16x8*)&xA[wr * 64 + f * 16 + l15][ks * 32 + kl * 8];
        #pragma unroll
        for (int f = 0; f < 2; ++f)
            bb[f] = *(const s16x8*)&Ws[wc * 32 + f * 16 + l15][ks * 32 + kl * 8];
        #pragma unroll
        for (int fr = 0; fr < 4; ++fr)
            #pragma unroll
            for (int fc = 0; fc < 2; ++fc)
                acc[fr][fc] = __builtin_amdgcn_mfma_f32_16x16x32_bf16(a[fr], bb[fc], acc[fr][fc], 0, 0, 0);
    }
    __syncthreads();

    // build xTl (transpose of xA) + sxp partials (hb==0); Wt region is dead
    {
        const int i = tid >> 1, q = tid & 1;
        float sacc = 0.f;
        unsigned short t64[64] __attribute__((aligned(16)));
        #pragma unroll
        for (int m = 0; m < 64; ++m) {
            const unsigned short u = xA[q * 64 + m][i];
            sacc += bf2f(u);
            t64[m] = u;
        }
        #pragma unroll
        for (int v = 0; v < 8; ++v)
            *(u16x8*)&xTl[i][q * 64 + v * 8] = *(u16x8*)&t64[v * 8];
        if (hb == 0)
            sxp[(size_t)((sh * 2 + q) * 16 + b) * 128 + i] = sacc;
    }
    __syncthreads();

    // write hts (relu, bf16, [hid 64][tok 128]) into Ws region
    #pragma unroll
    for (int fr = 0; fr < 4; ++fr)
        #pragma unroll
        for (int fc = 0; fc < 2; ++fc)
            #pragma unroll
            for (int j = 0; j < 4; ++j) {
                const int tok = wr * 64 + fr * 16 + kl * 4 + j;
                const int hid = wc * 32 + fc * 16 + l15;
                const float v = acc[fr][fc][j] + b1s[hid];
                hts[hid][tok] = f2bf(v > 0.f ? v : 0.f);
            }
    __syncthreads();

    // GEMM2: Mp[sh][b][hb*64+h][i] = hts @ xTl; wave tile 32x64
    f32x4 acc2[2][4];
    #pragma unroll
    for (int i = 0; i < 2; ++i)
        #pragma unroll
        for (int j = 0; j < 4; ++j) acc2[i][j] = zero;
    #pragma unroll
    for (int ks = 0; ks < 4; ++ks) {
        s16x8 a2[2], b2f[4];
        #pragma unroll
        for (int f = 0; f < 2; ++f)
            a2[f] = *(const s16x8*)&hts[wr * 32 + f * 16 + l15][ks * 32 + kl * 8];
        #pragma unroll
        for (int f = 0; f < 4; ++f)
            b2f[f] = *(const s16x8*)&xTl[wc * 64 + f * 16 + l15][ks * 32 + kl * 8];
        #pragma unroll
        for (int fr = 0; fr < 2; ++fr)
            #pragma unroll
            for (int fc = 0; fc < 4; ++fc)
                acc2[fr][fc] = __builtin_amdgcn_mfma_f32_16x16x32_bf16(a2[fr], b2f[fc], acc2[fr][fc], 0, 0, 0);
    }
    const size_t mpbase = (size_t)(sh * 16 + b) * 65536;
    #pragma unroll
    for (int fr = 0; fr < 2; ++fr)
        #pragma unroll
        for (int fc = 0; fc < 4; ++fc)
            #pragma unroll
            for (int j = 0; j < 4; ++j) {
                const int h = hb * 64 + wr * 32 + fr * 16 + kl * 4 + j;
                const int i = wc * 64 + fc * 16 + l15;
                Mp[mpbase + (size_t)h * 128 + i] = acc2[fr][fc][j];
            }
}

// ---------- Stage C (R17): K-across-warps, W2 read once/block ----------
__global__ __launch_bounds__(256) void k_C(const float* __restrict__ Mp,
        const float* __restrict__ W2, float* __restrict__ part) {
    __shared__ float Ms[16][128];
    __shared__ float red[4][16][128];
    const int tid = threadIdx.x;
    const int p = blockIdx.x;
    const int k0 = p * 128;
    #pragma unroll
    for (int r = 0; r < 8; ++r) {
        const int flat = r * 256 + tid;
        const int b = flat >> 7, kk = flat & 127;
        Ms[b][kk] = Mp[(size_t)b * 65536 + k0 + kk]
                  + Mp[(size_t)(16 + b) * 65536 + k0 + kk];
    }
    __syncthreads();
    const int lane = tid & 63, w = tid >> 6;
    const int o2 = lane * 2;
    float2 acc[16];
    #pragma unroll
    for (int b = 0; b < 16; ++b) acc[b] = {0.f, 0.f};
    #pragma unroll 2
    for (int jt = 0; jt < 8; ++jt) {
        float2 wst[4];
        #pragma unroll
        for (int j = 0; j < 4; ++j)
            wst[j] = *(const float2*)&W2[(size_t)(k0 + w * 32 + jt * 4 + j) * 128 + o2];
        #pragma unroll
        for (int b = 0; b < 16; ++b) {
            const float4 mv = *(const float4*)&Ms[b][w * 32 + jt * 4];
            acc[b].x += mv.x * wst[0].x + mv.y * wst[1].x + mv.z * wst[2].x + mv.w * wst[3].x;
            acc[b].y += mv.x * wst[0].y + mv.y * wst[1].y + mv.z * wst[2].y + mv.w * wst[3].y;
        }
    }
    #pragma unroll
    for (int b = 0; b < 16; ++b)
        *(float2*)&red[w][b][o2] = acc[b];
    __syncthreads();
    {
        const int b  = tid >> 4;
        const int o0 = (tid & 15) * 8;
        float v[8];
        #pragma unroll
        for (int j = 0; j < 8; ++j)
            v[j] = red[0][b][o0 + j] + red[1][b][o0 + j]
                 + red[2][b][o0 + j] + red[3][b][o0 + j];
        float* dst = &part[(size_t)(p * 16 + b) * 128 + o0];
        *(float4*)dst       = *(float4*)&v[0];
        *(float4*)(dst + 4) = *(float4*)&v[4];
    }
}

// ---------- Stage D: reduce 512 partials + b2 term + Wfc + bfc (1024 thr, 8 groups) ----------
__global__ __launch_bounds__(1024) void k_D(const float* __restrict__ part,
        const float* __restrict__ sxp, const float* __restrict__ b2,
        const float* __restrict__ Wfc, const float* __restrict__ bfc,
        float* __restrict__ out) {
    __shared__ float sh[8][128];
    __shared__ float sxs[128];
    __shared__ float ysum[128];
    __shared__ float ysh[128];
    const int b = blockIdx.x;
    const int t = threadIdx.x & 127;
    const int g = threadIdx.x >> 7;
    float y = 0.f;
    #pragma unroll 8
    for (int pp = g * 64; pp < g * 64 + 64; ++pp)
        y += part[(size_t)(pp * 16 + b) * 128 + t];
    sh[g][t] = y;
    __syncthreads();
    if (g == 0) {
        float yy = sh[0][t];
        #pragma unroll
        for (int j = 1; j < 8; ++j) yy += sh[j][t];
        ysum[t] = yy;
        sxs[t] = sxp[(size_t)(0 * 16 + b) * 128 + t] + sxp[(size_t)(1 * 16 + b) * 128 + t]
               + sxp[(size_t)(2 * 16 + b) * 128 + t] + sxp[(size_t)(3 * 16 + b) * 128 + t];
    }
    __syncthreads();
    float yb = 0.f;
    #pragma unroll
    for (int i = g * 16; i < g * 16 + 16; ++i)
        yb += sxs[i] * b2[i * 128 + t];
    sh[g][t] = yb;
    __syncthreads();
    if (g == 0) {
        float yy = ysum[t];
        #pragma unroll
        for (int j = 0; j < 8; ++j) yy += sh[j][t];
        ysh[t] = yy;
    }
    __syncthreads();
    float f = 0.f;
    #pragma unroll
    for (int oo = g * 16; oo < g * 16 + 16; ++oo)
        f += ysh[oo] * Wfc[oo * 128 + t];
    sh[g][t] = f;
    __syncthreads();
    if (g == 0) {
        float s = bfc[t];
        #pragma unroll
        for (int j = 0; j < 8; ++j) s += sh[j][t];
        out[b * 128 + t] = s;
    }
}

extern "C" void kernel_launch(void* const* d_in, const int* in_sizes, int n_in,
                              void* d_out, int out_size, void* d_ws, size_t ws_size,
                              hipStream_t stream) {
    const float* x   = (const float*)d_in[0];
    const float* W1  = (const float*)d_in[1];
    const float* b1  = (const float*)d_in[2];
    const float* W2  = (const float*)d_in[3];
    const float* b2  = (const float*)d_in[4];
    const float* Wfc = (const float*)d_in[5];
    const float* bfc = (const float*)d_in[6];
    float* ws  = (float*)d_ws;
    float* Mp   = ws + OFF_MP;
    float* part = ws + OFF_PART;
    float* sxp  = ws + OFF_SXP;
    float* out  = (float*)d_out;

    // DIAGNOSTIC: run the identical chain 3x (idempotent, deterministic).
    // dur = F + 3K vs R17's F + K  ->  K = (dur - 33.2)/2, F = 33.2 - K.
    for (int rep = 0; rep < 3; ++rep) {
        k_AB<<<256, 256, 0, stream>>>(x, W1, b1, Mp, sxp);
        k_C <<<512, 256, 0, stream>>>(Mp, W2, part);
        k_D <<<16, 1024, 0, stream>>>(part, sxp, b2, Wfc, bfc, out);
    }
}

// Round 19
// 49.075 us; speedup vs baseline: 1.8210x; 1.8210x over previous
//
#include <hip/hip_runtime.h>

// B=16, S=256, IN=128, OUT=128, HID=512
// DIAGNOSTIC ROUND 2: k_C body runs 4x inside one dispatch (3 rotated dummy
// reps kept live via asm, 4th is the real one) so k_C's counters appear in
// the top-5. k_AB / k_D frozen at R17. dur ~ 33 + 3*C.

typedef __attribute__((ext_vector_type(8))) short     s16x8;
typedef __attribute__((ext_vector_type(8))) unsigned short u16x8;
typedef __attribute__((ext_vector_type(4))) float     f32x4;

__device__ __forceinline__ unsigned short f2bf(float f) {
    union { float f; unsigned int u; } v; v.f = f;
    unsigned int r = v.u + 0x7FFFu + ((v.u >> 16) & 1u);   // RNE
    return (unsigned short)(r >> 16);
}
__device__ __forceinline__ float bf2f(unsigned short u) {
    union { unsigned int u; float f; } v; v.u = ((unsigned int)u) << 16;
    return v.f;
}

// ws float offsets
#define OFF_MP   0          // Mp   f32 [2][16][65536] -> 2097152 f
#define OFF_PART 2097152    // part f32 [512][16][128] -> 1048576 f
#define OFF_SXP  3145728    // sxp  f32 [4][16][128]   -> 8192 f

// ---------- Stage AB (R13-proven): GEMM1 (x@W1 -> h in LDS) + GEMM2 (h^T@x -> Mp) ----------
__global__ __launch_bounds__(256) void k_AB(const float* __restrict__ x,
        const float* __restrict__ W1, const float* __restrict__ b1,
        float* __restrict__ Mp, float* __restrict__ sxp) {
    __shared__ __align__(16) unsigned char smem[87296];
    auto Ws  = (unsigned short (*)[136])(smem);            // [64][136] hid x i
    auto xA  = (unsigned short (*)[136])(smem + 17408);    // [128][136] s x i
    auto xTl = (unsigned short (*)[136])(smem + 52224);    // [128][136] i x s
    auto Wt  = (float (*)[33])(smem + 52224);              // f32 staging (alias xTl)
    float* b1s = (float*)(smem + 87040);
    auto hts = (unsigned short (*)[136])(smem);            // [64][136] alias Ws

    const int tid = threadIdx.x;
    const int b  = blockIdx.x >> 4;
    const int hb = (blockIdx.x >> 1) & 7;
    const int sh = blockIdx.x & 1;

    {
        const int r = tid >> 1, q = tid & 1;
        const float* xrow = &x[(size_t)(b * 256 + sh * 128 + r) * 128 + q * 64];
        #pragma unroll
        for (int m = 0; m < 8; ++m) {
            const float4 v0 = *(const float4*)&xrow[m * 8];
            const float4 v1 = *(const float4*)&xrow[m * 8 + 4];
            unsigned short t8[8] __attribute__((aligned(16))) = {
                f2bf(v0.x), f2bf(v0.y), f2bf(v0.z), f2bf(v0.w),
                f2bf(v1.x), f2bf(v1.y), f2bf(v1.z), f2bf(v1.w)};
            *(u16x8*)&xA[r][q * 64 + m * 8] = *(u16x8*)t8;
        }
        if (tid < 64) b1s[tid] = b1[hb * 64 + tid];
    }
    for (int hq = 0; hq < 2; ++hq) {
        __syncthreads();
        #pragma unroll
        for (int p = 0; p < 16; ++p) {
            const int flat = p * 256 + tid;
            const int i = flat >> 5, hc = flat & 31;
            Wt[i][hc] = W1[(size_t)i * 512 + hb * 64 + hq * 32 + hc];
        }
        __syncthreads();
        {
            const int h2 = tid >> 3, pt = tid & 7;
            unsigned short t16[16] __attribute__((aligned(16)));
            #pragma unroll
            for (int m = 0; m < 16; ++m)
                t16[m] = f2bf(Wt[pt * 16 + m][h2]);
            *(u16x8*)&Ws[hq * 32 + h2][pt * 16]     = *(u16x8*)&t16[0];
            *(u16x8*)&Ws[hq * 32 + h2][pt * 16 + 8] = *(u16x8*)&t16[8];
        }
    }
    __syncthreads();

    const int w = tid >> 6, lane = tid & 63;
    const int wr = w >> 1, wc = w & 1;
    const int l15 = lane & 15, kl = lane >> 4;
    f32x4 zero = {0.f, 0.f, 0.f, 0.f};

    // GEMM1: C[tok 128][hid 64]; wave tile 64x32
    f32x4 acc[4][2];
    #pragma unroll
    for (int i = 0; i < 4; ++i)
        #pragma unroll
        for (int j = 0; j < 2; ++j) acc[i][j] = zero;
    #pragma unroll
    for (int ks = 0; ks < 4; ++ks) {
        s16x8 a[4], bb[2];
        #pragma unroll
        for (int f = 0; f < 4; ++f)
            a[f] = *(const s16x8*)&xA[wr * 64 + f * 16 + l15][ks * 32 + kl * 8];
        #pragma unroll
        for (int f = 0; f < 2; ++f)
            bb[f] = *(const s16x8*)&Ws[wc * 32 + f * 16 + l15][ks * 32 + kl * 8];
        #pragma unroll
        for (int fr = 0; fr < 4; ++fr)
            #pragma unroll
            for (int fc = 0; fc < 2; ++fc)
                acc[fr][fc] = __builtin_amdgcn_mfma_f32_16x16x32_bf16(a[fr], bb[fc], acc[fr][fc], 0, 0, 0);
    }
    __syncthreads();

    // build xTl (transpose of xA) + sxp partials (hb==0); Wt region is dead
    {
        const int i = tid >> 1, q = tid & 1;
        float sacc = 0.f;
        unsigned short t64[64] __attribute__((aligned(16)));
        #pragma unroll
        for (int m = 0; m < 64; ++m) {
            const unsigned short u = xA[q * 64 + m][i];
            sacc += bf2f(u);
            t64[m] = u;
        }
        #pragma unroll
        for (int v = 0; v < 8; ++v)
            *(u16x8*)&xTl[i][q * 64 + v * 8] = *(u16x8*)&t64[v * 8];
        if (hb == 0)
            sxp[(size_t)((sh * 2 + q) * 16 + b) * 128 + i] = sacc;
    }
    __syncthreads();

    // write hts (relu, bf16, [hid 64][tok 128]) into Ws region
    #pragma unroll
    for (int fr = 0; fr < 4; ++fr)
        #pragma unroll
        for (int fc = 0; fc < 2; ++fc)
            #pragma unroll
            for (int j = 0; j < 4; ++j) {
                const int tok = wr * 64 + fr * 16 + kl * 4 + j;
                const int hid = wc * 32 + fc * 16 + l15;
                const float v = acc[fr][fc][j] + b1s[hid];
                hts[hid][tok] = f2bf(v > 0.f ? v : 0.f);
            }
    __syncthreads();

    // GEMM2: Mp[sh][b][hb*64+h][i] = hts @ xTl; wave tile 32x64
    f32x4 acc2[2][4];
    #pragma unroll
    for (int i = 0; i < 2; ++i)
        #pragma unroll
        for (int j = 0; j < 4; ++j) acc2[i][j] = zero;
    #pragma unroll
    for (int ks = 0; ks < 4; ++ks) {
        s16x8 a2[2], b2f[4];
        #pragma unroll
        for (int f = 0; f < 2; ++f)
            a2[f] = *(const s16x8*)&hts[wr * 32 + f * 16 + l15][ks * 32 + kl * 8];
        #pragma unroll
        for (int f = 0; f < 4; ++f)
            b2f[f] = *(const s16x8*)&xTl[wc * 64 + f * 16 + l15][ks * 32 + kl * 8];
        #pragma unroll
        for (int fr = 0; fr < 2; ++fr)
            #pragma unroll
            for (int fc = 0; fc < 4; ++fc)
                acc2[fr][fc] = __builtin_amdgcn_mfma_f32_16x16x32_bf16(a2[fr], b2f[fc], acc2[fr][fc], 0, 0, 0);
    }
    const size_t mpbase = (size_t)(sh * 16 + b) * 65536;
    #pragma unroll
    for (int fr = 0; fr < 2; ++fr)
        #pragma unroll
        for (int fc = 0; fc < 4; ++fc)
            #pragma unroll
            for (int j = 0; j < 4; ++j) {
                const int h = hb * 64 + wr * 32 + fr * 16 + kl * 4 + j;
                const int i = wc * 64 + fc * 16 + l15;
                Mp[mpbase + (size_t)h * 128 + i] = acc2[fr][fc][j];
            }
}

// ---------- Stage C DIAGNOSTIC: R17 body x4 (3 rotated live dummies + 1 real) ----------
__global__ __launch_bounds__(256) void k_C_x4(const float* __restrict__ Mp,
        const float* __restrict__ W2, float* __restrict__ part) {
    __shared__ float Ms[16][128];
    __shared__ float red[4][16][128];
    const int tid = threadIdx.x;
    const int lane = tid & 63, w = tid >> 6;
    const int o2 = lane * 2;
    float2 acc[16];
    float guard = 0.f;
    for (int rep = 0; rep < 4; ++rep) {
        // reps 0..2: rotated slices (discarded, kept live); rep 3: pb == blockIdx.x
        const int pb = (int)((blockIdx.x + (unsigned)(rep + 1) * 128u) & 511u);
        const int k0 = pb * 128;
        __syncthreads();
        #pragma unroll
        for (int r = 0; r < 8; ++r) {
            const int flat = r * 256 + tid;
            const int b = flat >> 7, kk = flat & 127;
            Ms[b][kk] = Mp[(size_t)b * 65536 + k0 + kk]
                      + Mp[(size_t)(16 + b) * 65536 + k0 + kk];
        }
        __syncthreads();
        #pragma unroll
        for (int b = 0; b < 16; ++b) acc[b] = {0.f, 0.f};
        #pragma unroll 2
        for (int jt = 0; jt < 8; ++jt) {
            float2 wst[4];
            #pragma unroll
            for (int j = 0; j < 4; ++j)
                wst[j] = *(const float2*)&W2[(size_t)(k0 + w * 32 + jt * 4 + j) * 128 + o2];
            #pragma unroll
            for (int b = 0; b < 16; ++b) {
                const float4 mv = *(const float4*)&Ms[b][w * 32 + jt * 4];
                acc[b].x += mv.x * wst[0].x + mv.y * wst[1].x + mv.z * wst[2].x + mv.w * wst[3].x;
                acc[b].y += mv.x * wst[0].y + mv.y * wst[1].y + mv.z * wst[2].y + mv.w * wst[3].y;
            }
        }
        guard += acc[0].x + acc[7].y + acc[15].x;
        asm volatile("" : "+v"(guard));   // keep dummy reps live (rule #17); no cost
    }
    // write using last rep's acc (its pb == blockIdx.x) — identical math to R17
    #pragma unroll
    for (int b = 0; b < 16; ++b)
        *(float2*)&red[w][b][o2] = acc[b];
    __syncthreads();
    {
        const int b  = tid >> 4;
        const int o0 = (tid & 15) * 8;
        float v[8];
        #pragma unroll
        for (int j = 0; j < 8; ++j)
            v[j] = red[0][b][o0 + j] + red[1][b][o0 + j]
                 + red[2][b][o0 + j] + red[3][b][o0 + j];
        float* dst = &part[(size_t)(blockIdx.x * 16 + b) * 128 + o0];
        *(float4*)dst       = *(float4*)&v[0];
        *(float4*)(dst + 4) = *(float4*)&v[4];
    }
}

// ---------- Stage D: reduce 512 partials + b2 term + Wfc + bfc (1024 thr, 8 groups) ----------
__global__ __launch_bounds__(1024) void k_D(const float* __restrict__ part,
        const float* __restrict__ sxp, const float* __restrict__ b2,
        const float* __restrict__ Wfc, const float* __restrict__ bfc,
        float* __restrict__ out) {
    __shared__ float sh[8][128];
    __shared__ float sxs[128];
    __shared__ float ysum[128];
    __shared__ float ysh[128];
    const int b = blockIdx.x;
    const int t = threadIdx.x & 127;
    const int g = threadIdx.x >> 7;
    float y = 0.f;
    #pragma unroll 8
    for (int pp = g * 64; pp < g * 64 + 64; ++pp)
        y += part[(size_t)(pp * 16 + b) * 128 + t];
    sh[g][t] = y;
    __syncthreads();
    if (g == 0) {
        float yy = sh[0][t];
        #pragma unroll
        for (int j = 1; j < 8; ++j) yy += sh[j][t];
        ysum[t] = yy;
        sxs[t] = sxp[(size_t)(0 * 16 + b) * 128 + t] + sxp[(size_t)(1 * 16 + b) * 128 + t]
               + sxp[(size_t)(2 * 16 + b) * 128 + t] + sxp[(size_t)(3 * 16 + b) * 128 + t];
    }
    __syncthreads();
    float yb = 0.f;
    #pragma unroll
    for (int i = g * 16; i < g * 16 + 16; ++i)
        yb += sxs[i] * b2[i * 128 + t];
    sh[g][t] = yb;
    __syncthreads();
    if (g == 0) {
        float yy = ysum[t];
        #pragma unroll
        for (int j = 0; j < 8; ++j) yy += sh[j][t];
        ysh[t] = yy;
    }
    __syncthreads();
    float f = 0.f;
    #pragma unroll
    for (int oo = g * 16; oo < g * 16 + 16; ++oo)
        f += ysh[oo] * Wfc[oo * 128 + t];
    sh[g][t] = f;
    __syncthreads();
    if (g == 0) {
        float s = bfc[t];
        #pragma unroll
        for (int j = 0; j < 8; ++j) s += sh[j][t];
        out[b * 128 + t] = s;
    }
}

extern "C" void kernel_launch(void* const* d_in, const int* in_sizes, int n_in,
                              void* d_out, int out_size, void* d_ws, size_t ws_size,
                              hipStream_t stream) {
    const float* x   = (const float*)d_in[0];
    const float* W1  = (const float*)d_in[1];
    const float* b1  = (const float*)d_in[2];
    const float* W2  = (const float*)d_in[3];
    const float* b2  = (const float*)d_in[4];
    const float* Wfc = (const float*)d_in[5];
    const float* bfc = (const float*)d_in[6];
    float* ws  = (float*)d_ws;
    float* Mp   = ws + OFF_MP;
    float* part = ws + OFF_PART;
    float* sxp  = ws + OFF_SXP;
    float* out  = (float*)d_out;

    k_AB  <<<256, 256, 0, stream>>>(x, W1, b1, Mp, sxp);
    k_C_x4<<<512, 256, 0, stream>>>(Mp, W2, part);
    k_D   <<<16, 1024, 0, stream>>>(part, sxp, b2, Wfc, bfc, out);
}

// Round 20
// 31.809 us; speedup vs baseline: 2.8095x; 1.5428x over previous
//
#include <hip/hip_runtime.h>

// B=16, S=256, IN=128, OUT=128, HID=512
// y[b,o] = sum_{k=h*128+i} M[b,k]*W2f[k*128+o] + sum_i sx[b,i]*b2[i*128+o]
//   M[b,h,i] = sum_s h[b,s,h]*x[b,s,i],  h = relu(x@W1+b1);  out = y@Wfc + bfc
// FINAL (R15 best, 32.07 us): AB (GEMM1+GEMM2 fused MFMA), C (8-deep staged W2
// stream), D (final reduce, 1024 thr).
// Cost model (R17-R19 diagnostics): F~11us fixed + 2 gaps x ~6us + AB~4 + C~5.3
// (L3 floor for 33.5MB W2) + D~1.5. Structural floor for a 3-stage dependency
// chain; in-kernel barriers cost more than they save (R8/R14: device-scope
// fences = per-block L2 writeback on non-coherent XCD L2s).

typedef __attribute__((ext_vector_type(8))) short     s16x8;
typedef __attribute__((ext_vector_type(8))) unsigned short u16x8;
typedef __attribute__((ext_vector_type(4))) float     f32x4;

__device__ __forceinline__ unsigned short f2bf(float f) {
    union { float f; unsigned int u; } v; v.f = f;
    unsigned int r = v.u + 0x7FFFu + ((v.u >> 16) & 1u);   // RNE
    return (unsigned short)(r >> 16);
}
__device__ __forceinline__ float bf2f(unsigned short u) {
    union { unsigned int u; float f; } v; v.u = ((unsigned int)u) << 16;
    return v.f;
}

// ws float offsets
#define OFF_MP   0          // Mp   f32 [2][16][65536] -> 2097152 f
#define OFF_PART 2097152    // part f32 [512][16][128] -> 1048576 f
#define OFF_SXP  3145728    // sxp  f32 [4][16][128]   -> 8192 f

// ---------- Stage AB: GEMM1 (x@W1 -> h in LDS) + GEMM2 (h^T@x -> Mp) ----------
__global__ __launch_bounds__(256) void k_AB(const float* __restrict__ x,
        const float* __restrict__ W1, const float* __restrict__ b1,
        float* __restrict__ Mp, float* __restrict__ sxp) {
    __shared__ __align__(16) unsigned char smem[87296];
    auto Ws  = (unsigned short (*)[136])(smem);            // [64][136] hid x i
    auto xA  = (unsigned short (*)[136])(smem + 17408);    // [128][136] s x i
    auto xTl = (unsigned short (*)[136])(smem + 52224);    // [128][136] i x s
    auto Wt  = (float (*)[33])(smem + 52224);              // f32 staging (alias xTl)
    float* b1s = (float*)(smem + 87040);
    auto hts = (unsigned short (*)[136])(smem);            // [64][136] alias Ws

    const int tid = threadIdx.x;
    const int b  = blockIdx.x >> 4;
    const int hb = (blockIdx.x >> 1) & 7;
    const int sh = blockIdx.x & 1;

    {
        const int r = tid >> 1, q = tid & 1;
        const float* xrow = &x[(size_t)(b * 256 + sh * 128 + r) * 128 + q * 64];
        #pragma unroll
        for (int m = 0; m < 8; ++m) {
            const float4 v0 = *(const float4*)&xrow[m * 8];
            const float4 v1 = *(const float4*)&xrow[m * 8 + 4];
            unsigned short t8[8] __attribute__((aligned(16))) = {
                f2bf(v0.x), f2bf(v0.y), f2bf(v0.z), f2bf(v0.w),
                f2bf(v1.x), f2bf(v1.y), f2bf(v1.z), f2bf(v1.w)};
            *(u16x8*)&xA[r][q * 64 + m * 8] = *(u16x8*)t8;
        }
        if (tid < 64) b1s[tid] = b1[hb * 64 + tid];
    }
    for (int hq = 0; hq < 2; ++hq) {
        __syncthreads();
        #pragma unroll
        for (int p = 0; p < 16; ++p) {
            const int flat = p * 256 + tid;
            const int i = flat >> 5, hc = flat & 31;
            Wt[i][hc] = W1[(size_t)i * 512 + hb * 64 + hq * 32 + hc];
        }
        __syncthreads();
        {
            const int h2 = tid >> 3, pt = tid & 7;
            unsigned short t16[16] __attribute__((aligned(16)));
            #pragma unroll
            for (int m = 0; m < 16; ++m)
                t16[m] = f2bf(Wt[pt * 16 + m][h2]);
            *(u16x8*)&Ws[hq * 32 + h2][pt * 16]     = *(u16x8*)&t16[0];
            *(u16x8*)&Ws[hq * 32 + h2][pt * 16 + 8] = *(u16x8*)&t16[8];
        }
    }
    __syncthreads();

    const int w = tid >> 6, lane = tid & 63;
    const int wr = w >> 1, wc = w & 1;
    const int l15 = lane & 15, kl = lane >> 4;
    f32x4 zero = {0.f, 0.f, 0.f, 0.f};

    // GEMM1: C[tok 128][hid 64]; wave tile 64x32
    f32x4 acc[4][2];
    #pragma unroll
    for (int i = 0; i < 4; ++i)
        #pragma unroll
        for (int j = 0; j < 2; ++j) acc[i][j] = zero;
    #pragma unroll
    for (int ks = 0; ks < 4; ++ks) {
        s16x8 a[4], bb[2];
        #pragma unroll
        for (int f = 0; f < 4; ++f)
            a[f] = *(const s16x8*)&xA[wr * 64 + f * 16 + l15][ks * 32 + kl * 8];
        #pragma unroll
        for (int f = 0; f < 2; ++f)
            bb[f] = *(const s16x8*)&Ws[wc * 32 + f * 16 + l15][ks * 32 + kl * 8];
        #pragma unroll
        for (int fr = 0; fr < 4; ++fr)
            #pragma unroll
            for (int fc = 0; fc < 2; ++fc)
                acc[fr][fc] = __builtin_amdgcn_mfma_f32_16x16x32_bf16(a[fr], bb[fc], acc[fr][fc], 0, 0, 0);
    }
    __syncthreads();

    // build xTl (transpose of xA) + sxp partials (hb==0); Wt region is dead
    {
        const int i = tid >> 1, q = tid & 1;
        float sacc = 0.f;
        unsigned short t64[64] __attribute__((aligned(16)));
        #pragma unroll
        for (int m = 0; m < 64; ++m) {
            const unsigned short u = xA[q * 64 + m][i];
            sacc += bf2f(u);
            t64[m] = u;
        }
        #pragma unroll
        for (int v = 0; v < 8; ++v)
            *(u16x8*)&xTl[i][q * 64 + v * 8] = *(u16x8*)&t64[v * 8];
        if (hb == 0)
            sxp[(size_t)((sh * 2 + q) * 16 + b) * 128 + i] = sacc;
    }
    __syncthreads();

    // write hts (relu, bf16, [hid 64][tok 128]) into Ws region
    #pragma unroll
    for (int fr = 0; fr < 4; ++fr)
        #pragma unroll
        for (int fc = 0; fc < 2; ++fc)
            #pragma unroll
            for (int j = 0; j < 4; ++j) {
                const int tok = wr * 64 + fr * 16 + kl * 4 + j;
                const int hid = wc * 32 + fc * 16 + l15;
                const float v = acc[fr][fc][j] + b1s[hid];
                hts[hid][tok] = f2bf(v > 0.f ? v : 0.f);
            }
    __syncthreads();

    // GEMM2: Mp[sh][b][hb*64+h][i] = hts @ xTl; wave tile 32x64
    f32x4 acc2[2][4];
    #pragma unroll
    for (int i = 0; i < 2; ++i)
        #pragma unroll
        for (int j = 0; j < 4; ++j) acc2[i][j] = zero;
    #pragma unroll
    for (int ks = 0; ks < 4; ++ks) {
        s16x8 a2[2], b2f[4];
        #pragma unroll
        for (int f = 0; f < 2; ++f)
            a2[f] = *(const s16x8*)&hts[wr * 32 + f * 16 + l15][ks * 32 + kl * 8];
        #pragma unroll
        for (int f = 0; f < 4; ++f)
            b2f[f] = *(const s16x8*)&xTl[wc * 64 + f * 16 + l15][ks * 32 + kl * 8];
        #pragma unroll
        for (int fr = 0; fr < 2; ++fr)
            #pragma unroll
            for (int fc = 0; fc < 4; ++fc)
                acc2[fr][fc] = __builtin_amdgcn_mfma_f32_16x16x32_bf16(a2[fr], b2f[fc], acc2[fr][fc], 0, 0, 0);
    }
    const size_t mpbase = (size_t)(sh * 16 + b) * 65536;
    #pragma unroll
    for (int fr = 0; fr < 2; ++fr)
        #pragma unroll
        for (int fc = 0; fc < 4; ++fc)
            #pragma unroll
            for (int j = 0; j < 4; ++j) {
                const int h = hb * 64 + wr * 32 + fr * 16 + kl * 4 + j;
                const int i = wc * 64 + fc * 16 + l15;
                Mp[mpbase + (size_t)h * 128 + i] = acc2[fr][fc][j];
            }
}

// ---------- Stage C: y-partials = Ms @ W2-rows, K=128/block, 512 blocks ----------
// Warp wb owns b-rows wb*4..+3; 64 lanes cover o via float2 (512 B/wave).
// W2 loads explicitly staged 8-deep (wbuf[8]) to keep 8 loads outstanding.
__global__ __launch_bounds__(256) void k_C(const float* __restrict__ Mp,
        const float* __restrict__ W2, float* __restrict__ part) {
    __shared__ float Ms[16][128];
    const int tid = threadIdx.x;
    const int p = blockIdx.x;
    const int k0 = p * 128;
    #pragma unroll
    for (int r = 0; r < 8; ++r) {
        const int flat = r * 256 + tid;
        const int b = flat >> 7, kk = flat & 127;
        Ms[b][kk] = Mp[(size_t)b * 65536 + k0 + kk]
                  + Mp[(size_t)(16 + b) * 65536 + k0 + kk];
    }
    __syncthreads();
    const int lane = tid & 63;
    const int wb   = tid >> 6;          // warp -> 4 b-rows
    const int o2   = lane * 2;
    float2 acc[4] = {{0.f,0.f},{0.f,0.f},{0.f,0.f},{0.f,0.f}};
    float2 wbuf[8];
    for (int kb = 0; kb < 128; kb += 8) {
        #pragma unroll
        for (int u = 0; u < 8; ++u)
            wbuf[u] = *(const float2*)&W2[(size_t)(k0 + kb + u) * 128 + o2];
        #pragma unroll
        for (int u = 0; u < 8; ++u) {
            #pragma unroll
            for (int bb = 0; bb < 4; ++bb) {
                const float m = Ms[wb * 4 + bb][kb + u];
                acc[bb].x += m * wbuf[u].x;
                acc[bb].y += m * wbuf[u].y;
            }
        }
    }
    #pragma unroll
    for (int bb = 0; bb < 4; ++bb)
        *(float2*)&part[(size_t)(p * 16 + wb * 4 + bb) * 128 + o2] = acc[bb];
}

// ---------- Stage D: reduce 512 partials + b2 term + Wfc + bfc (1024 thr, 8 groups) ----------
__global__ __launch_bounds__(1024) void k_D(const float* __restrict__ part,
        const float* __restrict__ sxp, const float* __restrict__ b2,
        const float* __restrict__ Wfc, const float* __restrict__ bfc,
        float* __restrict__ out) {
    __shared__ float sh[8][128];
    __shared__ float sxs[128];
    __shared__ float ysum[128];
    __shared__ float ysh[128];
    const int b = blockIdx.x;
    const int t = threadIdx.x & 127;
    const int g = threadIdx.x >> 7;
    float y = 0.f;
    #pragma unroll 8
    for (int pp = g * 64; pp < g * 64 + 64; ++pp)
        y += part[(size_t)(pp * 16 + b) * 128 + t];
    sh[g][t] = y;
    __syncthreads();
    if (g == 0) {
        float yy = sh[0][t];
        #pragma unroll
        for (int j = 1; j < 8; ++j) yy += sh[j][t];
        ysum[t] = yy;
        sxs[t] = sxp[(size_t)(0 * 16 + b) * 128 + t] + sxp[(size_t)(1 * 16 + b) * 128 + t]
               + sxp[(size_t)(2 * 16 + b) * 128 + t] + sxp[(size_t)(3 * 16 + b) * 128 + t];
    }
    __syncthreads();
    float yb = 0.f;
    #pragma unroll
    for (int i = g * 16; i < g * 16 + 16; ++i)
        yb += sxs[i] * b2[i * 128 + t];
    sh[g][t] = yb;
    __syncthreads();
    if (g == 0) {
        float yy = ysum[t];
        #pragma unroll
        for (int j = 0; j < 8; ++j) yy += sh[j][t];
        ysh[t] = yy;
    }
    __syncthreads();
    float f = 0.f;
    #pragma unroll
    for (int oo = g * 16; oo < g * 16 + 16; ++oo)
        f += ysh[oo] * Wfc[oo * 128 + t];
    sh[g][t] = f;
    __syncthreads();
    if (g == 0) {
        float s = bfc[t];
        #pragma unroll
        for (int j = 0; j < 8; ++j) s += sh[j][t];
        out[b * 128 + t] = s;
    }
}

extern "C" void kernel_launch(void* const* d_in, const int* in_sizes, int n_in,
                              void* d_out, int out_size, void* d_ws, size_t ws_size,
                              hipStream_t stream) {
    const float* x   = (const float*)d_in[0];
    const float* W1  = (const float*)d_in[1];
    const float* b1  = (const float*)d_in[2];
    const float* W2  = (const float*)d_in[3];
    const float* b2  = (const float*)d_in[4];
    const float* Wfc = (const float*)d_in[5];
    const float* bfc = (const float*)d_in[6];
    float* ws  = (float*)d_ws;
    float* Mp   = ws + OFF_MP;
    float* part = ws + OFF_PART;
    float* sxp  = ws + OFF_SXP;
    float* out  = (float*)d_out;

    k_AB<<<256, 256, 0, stream>>>(x, W1, b1, Mp, sxp);
    k_C <<<512, 256, 0, stream>>>(Mp, W2, part);
    k_D <<<16, 1024, 0, stream>>>(part, sxp, b2, Wfc, bfc, out);
}